// Round 1
// baseline (16286.501 us; speedup 1.0000x reference)
//
#include <hip/hip_runtime.h>

typedef unsigned short u16;
typedef unsigned int   u32;
typedef unsigned long long u64;
typedef __attribute__((ext_vector_type(8))) short  short8;
typedef __attribute__((ext_vector_type(4))) float  floatx4;

__device__ __forceinline__ u16 f2bf(float f){
  u32 x = __float_as_uint(f);
  x += 0x7fffu + ((x >> 16) & 1u);   // round-to-nearest-even
  return (u16)(x >> 16);
}
__device__ __forceinline__ u32 pk(float a, float b){
  return (u32)f2bf(a) | ((u32)f2bf(b) << 16);
}

// ---------------------------------------------------------------------------
// GEMM: C[M][N](f32) = A[M][K] @ B[N][K](f32)^T + bias1[N] (+ bias2[N]).
// A is f32 (a_f32=1, optional row indirection) or bf16 (a_f32=0).
// 128x128 tile, BK=32, 4 waves (2x2 of 64x64), mfma_f32_16x16x32_bf16.
// ---------------------------------------------------------------------------
#define TM 128
#define TN 128
#define BK 32
#define LDK 40   // +8 bf16 pad: keeps 16B alignment, breaks bank patterns

__global__ __launch_bounds__(256) void k_gemm(
    const void* __restrict__ Av, int a_f32, const int* __restrict__ a_rows,
    const float* __restrict__ B,
    const float* __restrict__ bias1, const float* __restrict__ bias2,
    float* __restrict__ outC,
    int M, int N, int K)
{
  __shared__ u16 As[TM][LDK];
  __shared__ u16 Bs[TN][LDK];
  const int tid  = threadIdx.x;
  const int n0   = blockIdx.x * TN;
  const int m0   = blockIdx.y * TM;
  const int wave = tid >> 6;
  const int lane = tid & 63;
  const int quad = lane >> 4;
  const int l16  = lane & 15;
  const int wm   = (wave >> 1) * 64;
  const int wn   = (wave & 1) * 64;

  const int srow = tid >> 1;
  const int scol = (tid & 1) * 16;
  int am = m0 + srow;
  if (a_rows) am = a_rows[am];
  const float* apf = (const float*)Av + (long)am * K + scol;
  const u16*   aph = (const u16*)Av + (long)am * K + scol;
  const float* bpf = B + (long)(n0 + srow) * K + scol;

  floatx4 acc[4][4] = {};

  for (int k0 = 0; k0 < K; k0 += BK){
    float4 b0 = *(const float4*)(bpf + k0);
    float4 b1 = *(const float4*)(bpf + k0 + 4);
    float4 b2 = *(const float4*)(bpf + k0 + 8);
    float4 b3 = *(const float4*)(bpf + k0 + 12);
    uint4 aS0, aS1;
    if (a_f32){
      float4 a0 = *(const float4*)(apf + k0);
      float4 a1 = *(const float4*)(apf + k0 + 4);
      float4 a2 = *(const float4*)(apf + k0 + 8);
      float4 a3 = *(const float4*)(apf + k0 + 12);
      aS0 = make_uint4(pk(a0.x,a0.y), pk(a0.z,a0.w), pk(a1.x,a1.y), pk(a1.z,a1.w));
      aS1 = make_uint4(pk(a2.x,a2.y), pk(a2.z,a2.w), pk(a3.x,a3.y), pk(a3.z,a3.w));
    } else {
      aS0 = *(const uint4*)(aph + k0);
      aS1 = *(const uint4*)(aph + k0 + 8);
    }
    uint4 bS0 = make_uint4(pk(b0.x,b0.y), pk(b0.z,b0.w), pk(b1.x,b1.y), pk(b1.z,b1.w));
    uint4 bS1 = make_uint4(pk(b2.x,b2.y), pk(b2.z,b2.w), pk(b3.x,b3.y), pk(b3.z,b3.w));
    __syncthreads();
    *(uint4*)&As[srow][scol]     = aS0;
    *(uint4*)&As[srow][scol + 8] = aS1;
    *(uint4*)&Bs[srow][scol]     = bS0;
    *(uint4*)&Bs[srow][scol + 8] = bS1;
    __syncthreads();
    short8 af[4], bfg[4];
    #pragma unroll
    for (int mt = 0; mt < 4; mt++) af[mt]  = *(const short8*)&As[wm + mt*16 + l16][quad*8];
    #pragma unroll
    for (int nt = 0; nt < 4; nt++) bfg[nt] = *(const short8*)&Bs[wn + nt*16 + l16][quad*8];
    #pragma unroll
    for (int mt = 0; mt < 4; mt++)
      #pragma unroll
      for (int nt = 0; nt < 4; nt++)
        acc[mt][nt] = __builtin_amdgcn_mfma_f32_16x16x32_bf16(af[mt], bfg[nt], acc[mt][nt], 0, 0, 0);
  }

  #pragma unroll
  for (int nt = 0; nt < 4; nt++){
    const int col = n0 + wn + nt*16 + l16;
    float bias = bias1[col];
    if (bias2) bias += bias2[col];
    #pragma unroll
    for (int mt = 0; mt < 4; mt++){
      #pragma unroll
      for (int r = 0; r < 4; r++){
        const int row = m0 + wm + mt*16 + quad*4 + r;
        outC[(long)row * N + col] = acc[mt][nt][r] + bias;
      }
    }
  }
}

// ---------------------------------------------------------------------------
// Fused dual-layer LSTM scan, software-pipelined across layers.
// 512 WGs (2/CU): blocks 0..255 = layer0 (b = idx&7, chunk = idx>>3),
// blocks 256..511 = layer1. Each WG owns 64 gate rows (16 hidden units x 4
// gates); W slices pinned in VGPRs via empty asm (layer1: W_ih1 + W_hh1 =
// 256 VGPRs). Weight preload uses per-p rotation (i+p)&31 so the 4 K-quarter
// groups read disjoint LDS bank quads in the dot (kills 4-way conflicts).
// Layer0 publishes h0[t] as bf16 history (agent-scope paired u32 stores) +
// per-batch done0 flag (release, own cache line). Layer1 folds the
// done0 >= t+2 wait into its end-of-step barrier spin, so the producer->
// consumer hop is a constant pipeline offset, not a per-step serial cost.
// Layer1 computes xg1 = W_ih1 @ h0[t] + b_ih1 + b_hh1 on the fly (f32).
// ---------------------------------------------------------------------------
__global__ __launch_bounds__(256, 2) void k_scan2(
    const float* __restrict__ xg,    // [4096][2048] f32 (layer0 input gates)
    const float* __restrict__ Whh0,  // [2048][512] f32
    const float* __restrict__ Wih1,  // [2048][512] f32
    const float* __restrict__ Whh1,  // [2048][512] f32
    const float* __restrict__ bih1,  // [2048]
    const float* __restrict__ bhh1,  // [2048]
    u16*        __restrict__ h0h,    // [4096][512] bf16 (live exchange L0->L1)
    u16*        __restrict__ h1h,    // [4096][512] bf16 (plain stores, FC GEMM)
    float*      __restrict__ hbuf,   // [2 layers][2 parity][8][512] f32
    int*        __restrict__ cnt)    // [0..255] L0 cnt, [256..511] L1 cnt,
                                     // [512+b*32] done0 flags
{
  const int tid   = threadIdx.x;
  const int layer = blockIdx.x >> 8;
  const int idx   = blockIdx.x & 255;
  const int b     = idx & 7;
  const int chunk = idx >> 3;
  const int c0    = chunk * 16;
  const int rr    = tid >> 2;          // 0..63 local gate-row
  const int g     = rr >> 4;           // 0..3 : i,f,g,o
  const int jj    = rr & 15;
  const int p     = tid & 3;           // K-quarter
  const int nrow  = g * 512 + c0 + jj;

  __shared__ __align__(16) float h_lds[512];
  __shared__ __align__(16) float x_lds[512];
  __shared__ float gates[64];
  __shared__ float c_lds[16];
  if (tid < 16) c_lds[tid] = 0.f;

  // recurrent-weight slice, bank-derotated, pinned in VGPRs
  const float* Whh = layer ? Whh1 : Whh0;
  float4 w[32];
  {
    const float4* wp = (const float4*)(Whh + (long)nrow * 512 + p * 128);
    #pragma unroll
    for (int i = 0; i < 32; i++) w[i] = wp[(i + p) & 31];
    #pragma unroll
    for (int i = 0; i < 32; i++)
      asm volatile("" : "+v"(w[i].x), "+v"(w[i].y), "+v"(w[i].z), "+v"(w[i].w));
  }
  float4 wx[32];
  float bias = 0.f;
  if (layer){
    const float4* wp = (const float4*)(Wih1 + (long)nrow * 512 + p * 128);
    #pragma unroll
    for (int i = 0; i < 32; i++) wx[i] = wp[(i + p) & 31];
    #pragma unroll
    for (int i = 0; i < 32; i++)
      asm volatile("" : "+v"(wx[i].x), "+v"(wx[i].y), "+v"(wx[i].z), "+v"(wx[i].w));
    bias = bih1[nrow] + bhh1[nrow];
  }

  int* cnt_me = cnt + layer * 256 + b * 32;
  int* done0  = cnt + 512 + b * 32;
  const long xgbase   = (long)b * 512 * 2048;
  const long histbase = (long)b * 512 * 512;
  int target = 0;

  if (layer){           // wait for h0[0]
    if (tid == 0){
      while (__hip_atomic_load(done0, __ATOMIC_ACQUIRE, __HIP_MEMORY_SCOPE_AGENT) < 1)
        __builtin_amdgcn_s_sleep(1);
    }
    __syncthreads();
  }

  for (int t = 0; t < 512; t++){
    float xgv = 0.f;
    if (layer){
      // h0[t] (guaranteed by done0 >= t+1 from previous end-of-step spin)
      u32 pr = __hip_atomic_load((const u32*)(h0h + histbase + (long)t * 512) + tid,
                                 __ATOMIC_RELAXED, __HIP_MEMORY_SCOPE_AGENT);
      x_lds[2*tid]     = __uint_as_float((pr & 0xffffu) << 16);
      x_lds[2*tid + 1] = __uint_as_float(pr & 0xffff0000u);
    } else if (p == 0){
      xgv = xg[xgbase + (long)t * 2048 + nrow];
    }
    if (t > 0){
      const u64* hsrc = (const u64*)(hbuf + ((layer*2 + ((t-1) & 1)) * 8 + b) * 512);
      u64 v = __hip_atomic_load(hsrc + tid, __ATOMIC_RELAXED, __HIP_MEMORY_SCOPE_AGENT);
      ((u64*)h_lds)[tid] = v;
    }
    __syncthreads();

    float s = 0.f;
    if (t > 0){
      const float* hp = h_lds + p * 128;
      #pragma unroll
      for (int i = 0; i < 32; i++){
        float4 h4 = *(const float4*)(hp + (((i + p) & 31) << 2));
        s += w[i].x * h4.x + w[i].y * h4.y + w[i].z * h4.z + w[i].w * h4.w;
      }
    }
    if (layer){
      const float* xp = x_lds + p * 128;
      #pragma unroll
      for (int i = 0; i < 32; i++){
        float4 h4 = *(const float4*)(xp + (((i + p) & 31) << 2));
        s += wx[i].x * h4.x + wx[i].y * h4.y + wx[i].z * h4.z + wx[i].w * h4.w;
      }
    }
    s += __shfl_xor(s, 1);
    s += __shfl_xor(s, 2);

    if (p == 0){
      float gv = (layer ? bias : xgv) + s;
      gv = (g == 2) ? tanhf(gv) : 1.f / (1.f + __expf(-gv));
      gates[rr] = gv;
    }
    __syncthreads();

    if (tid < 16){   // wave 0; release RMW below (same wave) drains these stores
      float iv = gates[tid], fv = gates[16 + tid], gg = gates[32 + tid], ov = gates[48 + tid];
      float c = fv * c_lds[tid] + iv * gg;
      c_lds[tid] = c;
      float h = ov * tanhf(c);
      __hip_atomic_store(hbuf + ((layer*2 + (t & 1)) * 8 + b) * 512 + c0 + tid, h,
                         __ATOMIC_RELAXED, __HIP_MEMORY_SCOPE_AGENT);
      if (layer){
        h1h[histbase + (long)t * 512 + c0 + tid] = f2bf(h);   // next-kernel consumer
      } else {
        float hn = __shfl_down(h, 1);
        if (!(tid & 1))
          __hip_atomic_store((u32*)(h0h + histbase + (long)t * 512 + c0 + tid),
                             pk(h, hn), __ATOMIC_RELAXED, __HIP_MEMORY_SCOPE_AGENT);
      }
    }

    target += 32;
    if (tid == 0){
      __hip_atomic_fetch_add(cnt_me, 1, __ATOMIC_RELEASE, __HIP_MEMORY_SCOPE_AGENT);
      for (;;){
        bool ok = __hip_atomic_load(cnt_me, __ATOMIC_ACQUIRE, __HIP_MEMORY_SCOPE_AGENT) >= target;
        if (ok && layer && t < 511)
          ok = __hip_atomic_load(done0, __ATOMIC_ACQUIRE, __HIP_MEMORY_SCOPE_AGENT) >= t + 2;
        if (ok) break;
        __builtin_amdgcn_s_sleep(1);
      }
      if (!layer && chunk == 0)   // acquire->release chain: h0 stores visible to L1
        __hip_atomic_store(done0, t + 1, __ATOMIC_RELEASE, __HIP_MEMORY_SCOPE_AGENT);
    }
    __syncthreads();
  }
}

__global__ void k_init(int* cnt){ cnt[threadIdx.x] = 0; }

// ---------------------------------------------------------------------------
extern "C" void kernel_launch(void* const* d_in, const int* in_sizes, int n_in,
                              void* d_out, int out_size, void* d_ws, size_t ws_size,
                              hipStream_t stream)
{
  const int*   ids  = (const int*)d_in[0];
  const float* emb  = (const float*)d_in[1];
  const float* Wih0 = (const float*)d_in[2];
  const float* Whh0 = (const float*)d_in[3];
  const float* bih0 = (const float*)d_in[4];
  const float* bhh0 = (const float*)d_in[5];
  const float* Wih1 = (const float*)d_in[6];
  const float* Whh1 = (const float*)d_in[7];
  const float* bih1 = (const float*)d_in[8];
  const float* bhh1 = (const float*)d_in[9];
  const float* Wfc  = (const float*)d_in[10];
  const float* bfc  = (const float*)d_in[11];
  float* out = (float*)d_out;

  char* ws = (char*)d_ws;
  float* xg   = (float*)(ws);                            // 33,554,432 B
  u16*   h0h  = (u16*) (ws + (size_t)33554432);          //  4,194,304 B
  u16*   h1h  = (u16*) (ws + (size_t)37748736);          //  4,194,304 B
  float* hbuf = (float*)(ws + (size_t)41943040);         //     65,536 B
  int*   cnt  = (int*)  (ws + (size_t)41943040 + 65536); //      4,096 B

  k_init<<<dim3(1), dim3(1024), 0, stream>>>(cnt);

  // xg0 = emb[ids] @ W_ih0^T + b_ih0 + b_hh0   (K=256, A=f32+indirect)
  k_gemm<<<dim3(16, 32), dim3(256), 0, stream>>>(
      (const void*)emb, 1, ids, Wih0, bih0, bhh0, xg, 4096, 2048, 256);

  // fused layer0+layer1 scan, pipelined (xg1 GEMM folded into layer1 step)
  k_scan2<<<dim3(512), dim3(256), 0, stream>>>(
      xg, Whh0, Wih1, Whh1, bih1, bhh1, h0h, h1h, hbuf, cnt);

  // logits = h1 @ W_fc^T + b_fc -> f32 d_out   (N=32000, A=bf16)
  k_gemm<<<dim3(250, 32), dim3(256), 0, stream>>>(
      (const void*)h1h, 0, (const int*)nullptr, Wfc, bfc, (const float*)nullptr,
      out, 4096, 32000, 512);
}